// Round 9
// baseline (139.444 us; speedup 1.0000x reference)
//
#include <hip/hip_runtime.h>
#include <hip/hip_bf16.h>

// context_mapping on MI355X — round 6 kernel, fourth submission (rounds 6-8
// all died on GPUAcquisitionTimeout — never executed, no signal).
// Shuffle-based inter-layer redistribution: replaces round-5's LDS bounce
// (TWO write->wait->read round-trips per tile on the critical path) with
// ds_bpermute (__shfl) gathers. Redistribution is a 4-lane-group permutation
// at px-stride 16: dest (g,px) needs z1 rows 8g..8g+7 = packed dwords of src
// lanes s0 = px + 16*((2g)&3), s1 = s0+16 (za for g<2, zq for g>=2).
// L3 needs no selects: g>=2 A-operand is zero-padded and shuffled lrelu
// outputs are always finite (0 * finite = 0, NaN-safe). LDS usage -> 0.

typedef __attribute__((ext_vector_type(8))) short bf16x8;
typedef __attribute__((ext_vector_type(4))) short s16x4;
typedef __attribute__((ext_vector_type(4))) float f32x4;

union B8 { bf16x8 v; short2 p[4]; int d[4]; };
union B4 { s16x4 v; short2 p[2]; int d[2]; };

__device__ __forceinline__ float lrelu(float x) { return fmaxf(x, 0.01f * x); }

__device__ __forceinline__ short2 cvt2(float a, float b) {
    __hip_bfloat162 h = __float22bfloat162_rn(make_float2(a, b));
    short2 s; __builtin_memcpy(&s, &h, 4); return s;
}

__global__ __launch_bounds__(256) void ctx_mfma(
    const float* __restrict__ lr,  const float* __restrict__ hr,
    const float* __restrict__ w0g, const float* __restrict__ w1g,
    const float* __restrict__ w2g, const float* __restrict__ w3g,
    const float* __restrict__ s0g, const float* __restrict__ s1g,
    const float* __restrict__ s2g, const float* __restrict__ wfg,
    float* __restrict__ out)
{
    constexpr int W = 1024, HW = 1024 * 1024, LHW = 256 * 256;

    const int tid  = threadIdx.x;
    const int lane = tid & 63;
    const int g    = lane >> 4;       // k-group 0..3
    const int px   = lane & 15;       // pixel-in-tile / weight-row index

    const int wave_id = blockIdx.x * 4 + (tid >> 6);
    const int y  = wave_id >> 3;          // one row per 8 waves
    const int xw = (wave_id & 7) << 7;    // 128-px span

    // ---- weight A-fragments (A[m=px][k=8g+j]) ----
    B8 a1[2][2];                           // L1: [o0-15 / o16-31][k-chunk]
    #pragma unroll
    for (int m = 0; m < 2; ++m)
        #pragma unroll
        for (int q = 0; q < 2; ++q) {
            const float* wp = w0g + (m * 16 + px) * 64 + q * 32 + g * 8;
            #pragma unroll
            for (int j = 0; j < 4; ++j) a1[m][q].p[j] = cvt2(wp[2 * j], wp[2 * j + 1]);
        }
    B8 a2;                                 // L2: W1 [16 x 32]
    {
        const float* wp = w1g + px * 32 + g * 8;
        #pragma unroll
        for (int j = 0; j < 4; ++j) a2.p[j] = cvt2(wp[2 * j], wp[2 * j + 1]);
    }
    B8 a3;                                 // L3: W2 [8 x 16] zero-padded to [16 x 32]
    {
        const bool val = (px < 8) && (g < 2);
        const float* wp = w2g + (px & 7) * 16 + (g & 1) * 8;   // always in-bounds
        const short2 z2s = make_short2(0, 0);
        #pragma unroll
        for (int j = 0; j < 4; ++j) a3.p[j] = val ? cvt2(wp[2 * j], wp[2 * j + 1]) : z2s;
    }
    const float4 w3v = *(const float4*)(w3g + (g & 1) * 4);    // L4 slice per k-group

    // ---- loop-invariant distance-net (depends only on px&3 and y&3) ----
    const int xi = px & 3, yi = y & 3;
    const float d0 = (float)xi + ((xi < 2) ? -2.f : -1.f);
    const float d1 = (float)yi + ((yi < 2) ? -2.f : -1.f);
    const float d2 = sqrtf(d0 * d0 + d1 * d1);
    const float q0 = lrelu(s0g[0] * d0 + s0g[1] * d1 + s0g[2] * d2);
    const float q1 = lrelu(s0g[3] * d0 + s0g[4] * d1 + s0g[5] * d2);
    const float q2 = lrelu(s0g[6] * d0 + s0g[7] * d1 + s0g[8] * d2);
    const float u0 = lrelu(s1g[0] * q0 + s1g[1] * q1 + s1g[2] * q2);
    const float u1 = lrelu(s1g[3] * q0 + s1g[4] * q1 + s1g[5] * q2);
    const float wt2 = lrelu(s2g[0] * u0 + s2g[1] * u1);
    const float awf0 = fabsf(wfg[0]), awf1 = fabsf(wfg[1]);

    // ---- shuffle source lanes for inter-layer redistribution ----
    const int s0l = px + 16 * ((2 * g) & 3);
    const int s1l = s0l + 16;
    const bool glo = (g < 2);

    // ---- per-lane load indices (advance by immediate per tile) ----
    const int cb = (g & 1) << 3;      // channel base 0 or 8
    int hr_idx[8], lr_idx[8];
    #pragma unroll
    for (int j = 0; j < 8; ++j) {
        hr_idx[j] = (cb + j) * HW  + y * W + xw + px;
        lr_idx[j] = (cb + j) * LHW + (y >> 2) * 256 + (xw >> 2) + (px >> 2);
    }
    const int oidx = y * W + xw + px;
    const f32x4 zf = {0.f, 0.f, 0.f, 0.f};

#define LOADT(LV, HV, T)                                                      \
    {                                                                         \
        _Pragma("unroll")                                                     \
        for (int j = 0; j < 8; ++j) {                                         \
            HV[j] = hr[hr_idx[j] + (T) * 16];                                 \
            LV[j] = lr[lr_idx[j] + (T) * 4];                                  \
        }                                                                     \
    }

#define COMPUTE(LV, HV, T)                                                    \
    {                                                                         \
        B8 b0, b1;                                                            \
        _Pragma("unroll")                                                     \
        for (int j = 0; j < 4; ++j) {                                         \
            float ua = glo ? LV[2 * j]     : HV[2 * j];                       \
            float ub = glo ? LV[2 * j + 1] : HV[2 * j + 1];                   \
            b0.p[j] = cvt2(ua, ub);                                           \
            float da = LV[2 * j]     - HV[2 * j];                             \
            float db = LV[2 * j + 1] - HV[2 * j + 1];                         \
            float pa = glo ? LV[2 * j]     * HV[2 * j]     : da * da;         \
            float pb = glo ? LV[2 * j + 1] * HV[2 * j + 1] : db * db;         \
            b1.p[j] = cvt2(pa, pb);                                           \
        }                                                                     \
        f32x4 acc1a = __builtin_amdgcn_mfma_f32_16x16x32_bf16(a1[0][0].v, b0.v, zf, 0, 0, 0); \
        acc1a = __builtin_amdgcn_mfma_f32_16x16x32_bf16(a1[0][1].v, b1.v, acc1a, 0, 0, 0);    \
        f32x4 acc1b = __builtin_amdgcn_mfma_f32_16x16x32_bf16(a1[1][0].v, b0.v, zf, 0, 0, 0); \
        acc1b = __builtin_amdgcn_mfma_f32_16x16x32_bf16(a1[1][1].v, b1.v, acc1b, 0, 0, 0);    \
        B4 za, zq;                                                            \
        za.p[0] = cvt2(lrelu(acc1a.x), lrelu(acc1a.y));                       \
        za.p[1] = cvt2(lrelu(acc1a.z), lrelu(acc1a.w));                       \
        zq.p[0] = cvt2(lrelu(acc1b.x), lrelu(acc1b.y));                       \
        zq.p[1] = cvt2(lrelu(acc1b.z), lrelu(acc1b.w));                       \
        /* z1 rows 8g..8g+7 at px: za/zq dwords of lanes s0l,s1l */           \
        int A0 = __shfl(za.d[0], s0l, 64);                                    \
        int A1 = __shfl(za.d[1], s0l, 64);                                    \
        int A2 = __shfl(za.d[0], s1l, 64);                                    \
        int A3 = __shfl(za.d[1], s1l, 64);                                    \
        int Q0 = __shfl(zq.d[0], s0l, 64);                                    \
        int Q1 = __shfl(zq.d[1], s0l, 64);                                    \
        int Q2 = __shfl(zq.d[0], s1l, 64);                                    \
        int Q3 = __shfl(zq.d[1], s1l, 64);                                    \
        B8 b2;                                                                \
        b2.d[0] = glo ? A0 : Q0;                                              \
        b2.d[1] = glo ? A1 : Q1;                                              \
        b2.d[2] = glo ? A2 : Q2;                                              \
        b2.d[3] = glo ? A3 : Q3;                                              \
        f32x4 acc2 = __builtin_amdgcn_mfma_f32_16x16x32_bf16(a2.v, b2.v, zf, 0, 0, 0); \
        B4 z2q;                                                               \
        z2q.p[0] = cvt2(lrelu(acc2.x), lrelu(acc2.y));                        \
        z2q.p[1] = cvt2(lrelu(acc2.z), lrelu(acc2.w));                        \
        /* z2 rows 8g..8g+7 (g<2); g>=2 pulls finite junk * A=0 -> 0 */       \
        B8 b3;                                                                \
        b3.d[0] = __shfl(z2q.d[0], s0l, 64);                                  \
        b3.d[1] = __shfl(z2q.d[1], s0l, 64);                                  \
        b3.d[2] = __shfl(z2q.d[0], s1l, 64);                                  \
        b3.d[3] = __shfl(z2q.d[1], s1l, 64);                                  \
        f32x4 acc3 = __builtin_amdgcn_mfma_f32_16x16x32_bf16(a3.v, b3.v, zf, 0, 0, 0); \
        float part = w3v.x * lrelu(acc3.x) + w3v.y * lrelu(acc3.y)            \
                   + w3v.z * lrelu(acc3.z) + w3v.w * lrelu(acc3.w);           \
        float sum = part + __shfl_xor(part, 16, 64);                          \
        float wt1 = lrelu(sum);                                               \
        float res = lrelu(awf0 * wt1 + awf1 * wt2);                           \
        if (g == 0) out[oidx + (T) * 16] = res;                               \
    }

    // ---- 2-deep software pipeline over 8 tiles ----
    float la[8], ha[8], lb[8], hb[8];
    LOADT(la, ha, 0);
    #pragma unroll
    for (int tt = 0; tt < 8; tt += 2) {
        LOADT(lb, hb, tt + 1);          // issue next-tile loads before chain
        COMPUTE(la, ha, tt);
        if (tt + 2 < 8) LOADT(la, ha, tt + 2);
        COMPUTE(lb, hb, tt + 1);
    }
#undef LOADT
#undef COMPUTE
}

extern "C" void kernel_launch(void* const* d_in, const int* in_sizes, int n_in,
                              void* d_out, int out_size, void* d_ws, size_t ws_size,
                              hipStream_t stream) {
    const float* lr = (const float*)d_in[0];
    const float* hr = (const float*)d_in[1];
    const float* w0 = (const float*)d_in[2];
    const float* w1 = (const float*)d_in[3];
    const float* w2 = (const float*)d_in[4];
    const float* w3 = (const float*)d_in[5];
    const float* s0 = (const float*)d_in[6];
    const float* s1 = (const float*)d_in[7];
    const float* s2 = (const float*)d_in[8];
    const float* wf = (const float*)d_in[9];
    float* o = (float*)d_out;

    // 65536 16-px tiles / 8 per wave = 8192 waves = 2048 blocks x 256 threads
    ctx_mfma<<<2048, 256, 0, stream>>>(lr, hr, w0, w1, w2, w3, s0, s1, s2, wf, o);
}

// Round 10
// 137.117 us; speedup vs baseline: 1.0170x; 1.0170x over previous
//
#include <hip/hip_runtime.h>
#include <hip/hip_bf16.h>

// context_mapping on MI355X — round 10: 4-tile load prefetch + 2-way compute ILP.
// Round-9 post-mortem: shuffle version == LDS version (47us) -> LDS bounce was
// never the critical path. Shared limiter: 1-tile prefetch depth (~500cy
// exposed HBM latency/tile) + fully serial per-tile chains (compiler refused
// interleave, VGPR stayed 60). Fix in source: COMPUTE2 hand-interleaves two
// independent tile chains statement-by-statement; 4 named load sets issue
// global loads 2-4 tiles ahead. ~165 VGPR, 3 waves/SIMD: ILP replaces TLP.

typedef __attribute__((ext_vector_type(8))) short bf16x8;
typedef __attribute__((ext_vector_type(4))) short s16x4;
typedef __attribute__((ext_vector_type(4))) float f32x4;

union B8 { bf16x8 v; short2 p[4]; int d[4]; };
union B4 { s16x4 v; short2 p[2]; int d[2]; };

__device__ __forceinline__ float lrelu(float x) { return fmaxf(x, 0.01f * x); }

__device__ __forceinline__ short2 cvt2(float a, float b) {
    __hip_bfloat162 h = __float22bfloat162_rn(make_float2(a, b));
    short2 s; __builtin_memcpy(&s, &h, 4); return s;
}

__global__ __launch_bounds__(256) void ctx_mfma(
    const float* __restrict__ lr,  const float* __restrict__ hr,
    const float* __restrict__ w0g, const float* __restrict__ w1g,
    const float* __restrict__ w2g, const float* __restrict__ w3g,
    const float* __restrict__ s0g, const float* __restrict__ s1g,
    const float* __restrict__ s2g, const float* __restrict__ wfg,
    float* __restrict__ out)
{
    constexpr int W = 1024, HW = 1024 * 1024, LHW = 256 * 256;

    const int tid  = threadIdx.x;
    const int lane = tid & 63;
    const int g    = lane >> 4;       // k-group 0..3
    const int px   = lane & 15;       // pixel-in-tile / weight-row index

    const int wave_id = blockIdx.x * 4 + (tid >> 6);
    const int y  = wave_id >> 3;          // one row per 8 waves
    const int xw = (wave_id & 7) << 7;    // 128-px span

    // ---- weight A-fragments (A[m=px][k=8g+j]) ----
    B8 a1[2][2];                           // L1: [o0-15 / o16-31][k-chunk]
    #pragma unroll
    for (int m = 0; m < 2; ++m)
        #pragma unroll
        for (int q = 0; q < 2; ++q) {
            const float* wp = w0g + (m * 16 + px) * 64 + q * 32 + g * 8;
            #pragma unroll
            for (int j = 0; j < 4; ++j) a1[m][q].p[j] = cvt2(wp[2 * j], wp[2 * j + 1]);
        }
    B8 a2;                                 // L2: W1 [16 x 32]
    {
        const float* wp = w1g + px * 32 + g * 8;
        #pragma unroll
        for (int j = 0; j < 4; ++j) a2.p[j] = cvt2(wp[2 * j], wp[2 * j + 1]);
    }
    B8 a3;                                 // L3: W2 [8 x 16] zero-padded to [16 x 32]
    {
        const bool val = (px < 8) && (g < 2);
        const float* wp = w2g + (px & 7) * 16 + (g & 1) * 8;   // always in-bounds
        const short2 z2s = make_short2(0, 0);
        #pragma unroll
        for (int j = 0; j < 4; ++j) a3.p[j] = val ? cvt2(wp[2 * j], wp[2 * j + 1]) : z2s;
    }
    const float4 w3v = *(const float4*)(w3g + (g & 1) * 4);    // L4 slice per k-group

    // ---- loop-invariant distance-net (depends only on px&3 and y&3) ----
    const int xi = px & 3, yi = y & 3;
    const float d0 = (float)xi + ((xi < 2) ? -2.f : -1.f);
    const float d1 = (float)yi + ((yi < 2) ? -2.f : -1.f);
    const float d2 = sqrtf(d0 * d0 + d1 * d1);
    const float q0 = lrelu(s0g[0] * d0 + s0g[1] * d1 + s0g[2] * d2);
    const float q1 = lrelu(s0g[3] * d0 + s0g[4] * d1 + s0g[5] * d2);
    const float q2 = lrelu(s0g[6] * d0 + s0g[7] * d1 + s0g[8] * d2);
    const float u0 = lrelu(s1g[0] * q0 + s1g[1] * q1 + s1g[2] * q2);
    const float u1 = lrelu(s1g[3] * q0 + s1g[4] * q1 + s1g[5] * q2);
    const float wt2 = lrelu(s2g[0] * u0 + s2g[1] * u1);
    const float awf0 = fabsf(wfg[0]), awf1 = fabsf(wfg[1]);

    // ---- shuffle source lanes for inter-layer redistribution ----
    const int s0l = px + 16 * ((2 * g) & 3);
    const int s1l = s0l + 16;
    const bool glo = (g < 2);

    // ---- per-lane load indices (advance by immediate per tile) ----
    const int cb = (g & 1) << 3;      // channel base 0 or 8
    int hr_idx[8], lr_idx[8];
    #pragma unroll
    for (int j = 0; j < 8; ++j) {
        hr_idx[j] = (cb + j) * HW  + y * W + xw + px;
        lr_idx[j] = (cb + j) * LHW + (y >> 2) * 256 + (xw >> 2) + (px >> 2);
    }
    const int oidx = y * W + xw + px;
    const f32x4 zf = {0.f, 0.f, 0.f, 0.f};

#define LOADT(LV, HV, T)                                                      \
    {                                                                         \
        _Pragma("unroll")                                                     \
        for (int j = 0; j < 8; ++j) {                                         \
            HV[j] = hr[hr_idx[j] + (T) * 16];                                 \
            LV[j] = lr[lr_idx[j] + (T) * 4];                                  \
        }                                                                     \
    }

#define BFRAG(LV, HV, B0, B1)                                                 \
    {                                                                         \
        _Pragma("unroll")                                                     \
        for (int j = 0; j < 4; ++j) {                                         \
            float ua = glo ? LV[2 * j]     : HV[2 * j];                       \
            float ub = glo ? LV[2 * j + 1] : HV[2 * j + 1];                   \
            B0.p[j] = cvt2(ua, ub);                                           \
            float da = LV[2 * j]     - HV[2 * j];                             \
            float db = LV[2 * j + 1] - HV[2 * j + 1];                         \
            float pa = glo ? LV[2 * j]     * HV[2 * j]     : da * da;         \
            float pb = glo ? LV[2 * j + 1] * HV[2 * j + 1] : db * db;         \
            B1.p[j] = cvt2(pa, pb);                                           \
        }                                                                     \
    }

// Two tiles, chains hand-interleaved so chain B's independent work covers
// chain A's MFMA / bpermute / load latencies (and vice versa).
#define COMPUTE2(LVA, HVA, LVB, HVB, TA, TB)                                  \
    {                                                                         \
        B8 b0A, b1A, b0B, b1B;                                                \
        BFRAG(LVA, HVA, b0A, b1A);                                            \
        f32x4 a1aA = __builtin_amdgcn_mfma_f32_16x16x32_bf16(a1[0][0].v, b0A.v, zf, 0, 0, 0); \
        a1aA = __builtin_amdgcn_mfma_f32_16x16x32_bf16(a1[0][1].v, b1A.v, a1aA, 0, 0, 0);     \
        f32x4 a1bA = __builtin_amdgcn_mfma_f32_16x16x32_bf16(a1[1][0].v, b0A.v, zf, 0, 0, 0); \
        a1bA = __builtin_amdgcn_mfma_f32_16x16x32_bf16(a1[1][1].v, b1A.v, a1bA, 0, 0, 0);     \
        BFRAG(LVB, HVB, b0B, b1B);                                            \
        f32x4 a1aB = __builtin_amdgcn_mfma_f32_16x16x32_bf16(a1[0][0].v, b0B.v, zf, 0, 0, 0); \
        a1aB = __builtin_amdgcn_mfma_f32_16x16x32_bf16(a1[0][1].v, b1B.v, a1aB, 0, 0, 0);     \
        f32x4 a1bB = __builtin_amdgcn_mfma_f32_16x16x32_bf16(a1[1][0].v, b0B.v, zf, 0, 0, 0); \
        a1bB = __builtin_amdgcn_mfma_f32_16x16x32_bf16(a1[1][1].v, b1B.v, a1bB, 0, 0, 0);     \
        B4 zaA, zqA;                                                          \
        zaA.p[0] = cvt2(lrelu(a1aA.x), lrelu(a1aA.y));                        \
        zaA.p[1] = cvt2(lrelu(a1aA.z), lrelu(a1aA.w));                        \
        zqA.p[0] = cvt2(lrelu(a1bA.x), lrelu(a1bA.y));                        \
        zqA.p[1] = cvt2(lrelu(a1bA.z), lrelu(a1bA.w));                        \
        int A0A = __shfl(zaA.d[0], s0l, 64);                                  \
        int A1A = __shfl(zaA.d[1], s0l, 64);                                  \
        int A2A = __shfl(zaA.d[0], s1l, 64);                                  \
        int A3A = __shfl(zaA.d[1], s1l, 64);                                  \
        int Q0A = __shfl(zqA.d[0], s0l, 64);                                  \
        int Q1A = __shfl(zqA.d[1], s0l, 64);                                  \
        int Q2A = __shfl(zqA.d[0], s1l, 64);                                  \
        int Q3A = __shfl(zqA.d[1], s1l, 64);                                  \
        B4 zaB, zqB;                                                          \
        zaB.p[0] = cvt2(lrelu(a1aB.x), lrelu(a1aB.y));                        \
        zaB.p[1] = cvt2(lrelu(a1aB.z), lrelu(a1aB.w));                        \
        zqB.p[0] = cvt2(lrelu(a1bB.x), lrelu(a1bB.y));                        \
        zqB.p[1] = cvt2(lrelu(a1bB.z), lrelu(a1bB.w));                        \
        int A0B = __shfl(zaB.d[0], s0l, 64);                                  \
        int A1B = __shfl(zaB.d[1], s0l, 64);                                  \
        int A2B = __shfl(zaB.d[0], s1l, 64);                                  \
        int A3B = __shfl(zaB.d[1], s1l, 64);                                  \
        int Q0B = __shfl(zqB.d[0], s0l, 64);                                  \
        int Q1B = __shfl(zqB.d[1], s0l, 64);                                  \
        int Q2B = __shfl(zqB.d[0], s1l, 64);                                  \
        int Q3B = __shfl(zqB.d[1], s1l, 64);                                  \
        B8 b2A;                                                               \
        b2A.d[0] = glo ? A0A : Q0A;                                           \
        b2A.d[1] = glo ? A1A : Q1A;                                           \
        b2A.d[2] = glo ? A2A : Q2A;                                           \
        b2A.d[3] = glo ? A3A : Q3A;                                           \
        f32x4 acc2A = __builtin_amdgcn_mfma_f32_16x16x32_bf16(a2.v, b2A.v, zf, 0, 0, 0); \
        B8 b2B;                                                               \
        b2B.d[0] = glo ? A0B : Q0B;                                           \
        b2B.d[1] = glo ? A1B : Q1B;                                           \
        b2B.d[2] = glo ? A2B : Q2B;                                           \
        b2B.d[3] = glo ? A3B : Q3B;                                           \
        f32x4 acc2B = __builtin_amdgcn_mfma_f32_16x16x32_bf16(a2.v, b2B.v, zf, 0, 0, 0); \
        B4 z2A;                                                               \
        z2A.p[0] = cvt2(lrelu(acc2A.x), lrelu(acc2A.y));                      \
        z2A.p[1] = cvt2(lrelu(acc2A.z), lrelu(acc2A.w));                      \
        B8 b3A;                                                               \
        b3A.d[0] = __shfl(z2A.d[0], s0l, 64);                                 \
        b3A.d[1] = __shfl(z2A.d[1], s0l, 64);                                 \
        b3A.d[2] = __shfl(z2A.d[0], s1l, 64);                                 \
        b3A.d[3] = __shfl(z2A.d[1], s1l, 64);                                 \
        B4 z2B;                                                               \
        z2B.p[0] = cvt2(lrelu(acc2B.x), lrelu(acc2B.y));                      \
        z2B.p[1] = cvt2(lrelu(acc2B.z), lrelu(acc2B.w));                      \
        B8 b3B;                                                               \
        b3B.d[0] = __shfl(z2B.d[0], s0l, 64);                                 \
        b3B.d[1] = __shfl(z2B.d[1], s0l, 64);                                 \
        b3B.d[2] = __shfl(z2B.d[0], s1l, 64);                                 \
        b3B.d[3] = __shfl(z2B.d[1], s1l, 64);                                 \
        f32x4 acc3A = __builtin_amdgcn_mfma_f32_16x16x32_bf16(a3.v, b3A.v, zf, 0, 0, 0); \
        f32x4 acc3B = __builtin_amdgcn_mfma_f32_16x16x32_bf16(a3.v, b3B.v, zf, 0, 0, 0); \
        float partA = w3v.x * lrelu(acc3A.x) + w3v.y * lrelu(acc3A.y)         \
                    + w3v.z * lrelu(acc3A.z) + w3v.w * lrelu(acc3A.w);        \
        float partB = w3v.x * lrelu(acc3B.x) + w3v.y * lrelu(acc3B.y)         \
                    + w3v.z * lrelu(acc3B.z) + w3v.w * lrelu(acc3B.w);        \
        float sumA = partA + __shfl_xor(partA, 16, 64);                       \
        float sumB = partB + __shfl_xor(partB, 16, 64);                       \
        float resA = lrelu(awf0 * lrelu(sumA) + awf1 * wt2);                  \
        float resB = lrelu(awf0 * lrelu(sumB) + awf1 * wt2);                  \
        if (g == 0) {                                                         \
            out[oidx + (TA) * 16] = resA;                                     \
            out[oidx + (TB) * 16] = resB;                                     \
        }                                                                     \
    }

    // ---- 4-deep load prefetch, 2-way-ILP compute over 8 tiles ----
    float la[8], ha[8], lb[8], hb[8], lc[8], hc[8], ld[8], hd[8];
    LOADT(la, ha, 0); LOADT(lb, hb, 1);
    LOADT(lc, hc, 2); LOADT(ld, hd, 3);
    COMPUTE2(la, ha, lb, hb, 0, 1);
    LOADT(la, ha, 4); LOADT(lb, hb, 5);     // reuse regs; WAR ok (reads done)
    COMPUTE2(lc, hc, ld, hd, 2, 3);
    LOADT(lc, hc, 6); LOADT(ld, hd, 7);
    COMPUTE2(la, ha, lb, hb, 4, 5);
    COMPUTE2(lc, hc, ld, hd, 6, 7);
#undef LOADT
#undef BFRAG
#undef COMPUTE2
}

extern "C" void kernel_launch(void* const* d_in, const int* in_sizes, int n_in,
                              void* d_out, int out_size, void* d_ws, size_t ws_size,
                              hipStream_t stream) {
    const float* lr = (const float*)d_in[0];
    const float* hr = (const float*)d_in[1];
    const float* w0 = (const float*)d_in[2];
    const float* w1 = (const float*)d_in[3];
    const float* w2 = (const float*)d_in[4];
    const float* w3 = (const float*)d_in[5];
    const float* s0 = (const float*)d_in[6];
    const float* s1 = (const float*)d_in[7];
    const float* s2 = (const float*)d_in[8];
    const float* wf = (const float*)d_in[9];
    float* o = (float*)d_out;

    // 65536 16-px tiles / 8 per wave = 8192 waves = 2048 blocks x 256 threads
    ctx_mfma<<<2048, 256, 0, stream>>>(lr, hr, w0, w1, w2, w3, s0, s1, s2, wf, o);
}